// Round 8
// baseline (329.700 us; speedup 1.0000x reference)
//
#include <hip/hip_runtime.h>
#include <hip/hip_bf16.h>

#define B_ 8192
#define F_ 2048
#define C_ 1000
#define CP 1024

typedef __attribute__((ext_vector_type(4))) float f32x4;
typedef __attribute__((ext_vector_type(8))) short bf16x8;
typedef __attribute__((ext_vector_type(8))) unsigned short u16x8;

__device__ __forceinline__ unsigned short f2bf(float f) {
    union { float f; unsigned int u; } x; x.f = f;
    unsigned int r = x.u + 0x7fffu + ((x.u >> 16) & 1u);
    return (unsigned short)(r >> 16);
}
__device__ __forceinline__ float bf2f(unsigned short h) {
    union { unsigned int u; float f; } x; x.u = ((unsigned int)h) << 16; return x.f;
}

template<int OP>
__device__ __forceinline__ float blockReduce(float v) {
    __shared__ float s[4];
    #pragma unroll
    for (int o = 32; o; o >>= 1) {
        float u = __shfl_down(v, o);
        v = (OP == 0) ? v + u : (OP == 1) ? fmaxf(v, u) : fminf(v, u);
    }
    __syncthreads();
    if ((threadIdx.x & 63) == 0) s[threadIdx.x >> 6] = v;
    __syncthreads();
    float r = s[0];
    #pragma unroll
    for (int i = 1; i < 4; i++) r = (OP == 0) ? r + s[i] : (OP == 1) ? fmaxf(r, s[i]) : fminf(r, s[i]);
    return r;
}

__device__ __forceinline__ void async16(const void* g, void* l) {
    __builtin_amdgcn_global_load_lds(
        (const __attribute__((address_space(1))) void*)g,
        (__attribute__((address_space(3))) void*)l, 16, 0, 0);
}

// ---------- merged prep (unchanged) ----------

__global__ __launch_bounds__(256) void k_prep(const float* __restrict__ x,
                                              const float* __restrict__ cent,
                                              const float* __restrict__ Whall,
                                              const float* __restrict__ Wsel,
                                              const float* __restrict__ Wcos,
                                              unsigned short* __restrict__ xbf,
                                              float* __restrict__ x2,
                                              float* __restrict__ direct,
                                              unsigned int* __restrict__ dmin,
                                              float* __restrict__ ssum,
                                              unsigned short* __restrict__ Bcat,
                                              unsigned short* __restrict__ cT,
                                              float* __restrict__ c2,
                                              unsigned short* __restrict__ wcos_bf) {
    const int bid = blockIdx.x, t = threadIdx.x;

    if (bid < 8192) {
        int row = bid;
        size_t base = (size_t)row * F_ + t * 8;
        float4 a = *(const float4*)(x + base);
        float4 b = *(const float4*)(x + base + 4);
        float v[8] = {a.x, a.y, a.z, a.w, b.x, b.y, b.z, b.w};
        u16x8 u; float ss = 0.f;
        #pragma unroll
        for (int j = 0; j < 8; j++) { ss += v[j] * v[j]; u[j] = f2bf(v[j]); }
        *(u16x8*)(xbf + base) = u;
        *(float4*)(direct + base) = a;
        *(float4*)(direct + base + 4) = b;
        ss = blockReduce<0>(ss);
        if (t == 0) { x2[row] = ss; dmin[row] = 0x7f7f7f7fu; ssum[row] = 0.0f; }
    } else if (bid < 9216) {
        int row = bid - 8192;
        size_t base = (size_t)row * F_ + t * 8;
        if (row < C_) {
            float4 a = *(const float4*)(cent + base);
            float4 b = *(const float4*)(cent + base + 4);
            float v[8] = {a.x, a.y, a.z, a.w, b.x, b.y, b.z, b.w};
            u16x8 u; float ss = 0.f;
            #pragma unroll
            for (int j = 0; j < 8; j++) { ss += v[j] * v[j]; u[j] = f2bf(v[j]); }
            *(u16x8*)(Bcat + base) = u;
            #pragma unroll
            for (int j = 0; j < 8; j++) cT[(size_t)(t * 8 + j) * CP + row] = u[j];
            ss = blockReduce<0>(ss);
            if (t == 0) c2[row] = ss;
        } else {
            u16x8 u;
            #pragma unroll
            for (int j = 0; j < 8; j++) u[j] = 0;
            *(u16x8*)(Bcat + base) = u;
            #pragma unroll
            for (int j = 0; j < 8; j++) cT[(size_t)(t * 8 + j) * CP + row] = 0;
            if (t == 0) c2[row] = 0.f;
        }
    } else if (bid < 10240) {
        int row = bid - 9216;
        size_t base = (size_t)row * F_ + t * 8;
        u16x8 u;
        if (row < C_) {
            float4 a = *(const float4*)(Whall + base);
            float4 b = *(const float4*)(Whall + base + 4);
            float v[8] = {a.x, a.y, a.z, a.w, b.x, b.y, b.z, b.w};
            #pragma unroll
            for (int j = 0; j < 8; j++) u[j] = f2bf(v[j]);
        } else {
            #pragma unroll
            for (int j = 0; j < 8; j++) u[j] = 0;
        }
        *(u16x8*)(Bcat + (size_t)1024 * F_ + base) = u;
    } else if (bid < 12288) {
        int row = bid - 10240;
        size_t base = (size_t)row * F_ + t * 8;
        float4 a = *(const float4*)(Wsel + base);
        float4 b = *(const float4*)(Wsel + base + 4);
        float v[8] = {a.x, a.y, a.z, a.w, b.x, b.y, b.z, b.w};
        u16x8 u;
        #pragma unroll
        for (int j = 0; j < 8; j++) u[j] = f2bf(v[j]);
        *(u16x8*)(Bcat + (size_t)2048 * F_ + base) = u;
    } else {
        int row = bid - 12288;
        size_t base = (size_t)row * F_ + t * 8;
        u16x8 u;
        if (row < C_) {
            float4 a = *(const float4*)(Wcos + base);
            float4 b = *(const float4*)(Wcos + base + 4);
            float v[8] = {a.x, a.y, a.z, a.w, b.x, b.y, b.z, b.w};
            float ss = 0.f;
            #pragma unroll
            for (int j = 0; j < 8; j++) ss += v[j] * v[j];
            ss = blockReduce<0>(ss);
            float sc = 16.0f / sqrtf(ss);
            #pragma unroll
            for (int j = 0; j < 8; j++) u[j] = f2bf(v[j] * sc);
        } else {
            #pragma unroll
            for (int j = 0; j < 8; j++) u[j] = 0;
        }
        *(u16x8*)(wcos_bf + base) = u;
    }
}

// ---------- shared GEMM machinery ----------

#define BAR() __builtin_amdgcn_s_barrier()
#define VMW(N) asm volatile("s_waitcnt vmcnt(" #N ")" ::: "memory")
#define PRIO1() __builtin_amdgcn_s_setprio(1)
#define PRIO0() __builtin_amdgcn_s_setprio(0)

#define LDA8O(dst, mh, off)                                                     \
    _Pragma("unroll")                                                           \
    for (int i_ = 0; i_ < 4; i_++) {                                            \
        dst[i_ * 2 + 0] = *(const bf16x8*)(pA0 + (off) + (mh) * 8192 + i_ * 2048); \
        dst[i_ * 2 + 1] = *(const bf16x8*)(pA1 + (off) + (mh) * 8192 + i_ * 2048); \
    }

#define LDB4O(dst, nh, off)                                                     \
    _Pragma("unroll")                                                           \
    for (int i_ = 0; i_ < 2; i_++) {                                            \
        dst[i_ * 2 + 0] = *(const bf16x8*)(pB0 + (off) + (nh) * 4096 + i_ * 2048); \
        dst[i_ * 2 + 1] = *(const bf16x8*)(pB1 + (off) + (nh) * 4096 + i_ * 2048); \
    }

#define STG_HALF(gp, half, ldsbase)                                             \
    _Pragma("unroll")                                                           \
    for (int i_ = 0; i_ < 2; i_++)                                              \
        async16((gp) + ((half) * 128 + i_ * 64) * (size_t)K,                    \
                (ldsbase) + (half) * 16384 + i_ * 8192);

#define MFMA16(a, b, mi0, ni0)                                                  \
    _Pragma("unroll")                                                           \
    for (int ks_ = 0; ks_ < 2; ks_++)                                           \
        _Pragma("unroll")                                                       \
        for (int i_ = 0; i_ < 4; i_++)                                          \
            _Pragma("unroll")                                                   \
            for (int j_ = 0; j_ < 2; j_++)                                      \
                acc[(mi0) + i_][(ni0) + j_] = __builtin_amdgcn_mfma_f32_16x16x32_bf16( \
                    a[i_ * 2 + ks_], b[j_ * 2 + ks_], acc[(mi0) + i_][(ni0) + j_], 0, 0, 0);

__device__ __forceinline__ float fast_tanh(float v) {
    float t = __expf(v + v);
    return (t - 1.0f) / (t + 1.0f);
}

// ---------- G1: 256x256 GEMM, m201-style 8-phase schedule ----------
// Per phase: {ds-reads | stage ONE half-tile} -> s_barrier -> setprio(1),
// 16 MFMA, setprio(0) -> s_barrier.  Counted VMW(4) ONLY at end of ph3/ph7
// (the sole compiler memory fences in the loop; plain s_barrier elsewhere so
// the compiler schedules freely -- R4/R5's regression came from fencing every
// barrier).  Staging one half-tile/phase, 2 tiles ahead:
//   ph0: B(T+1)h1->buf1  ph1: A(T+1)h1->buf1  ph2: B(T+2)h0->buf0
//   ph3: A(T+2)h0->buf0  ph4: B(T+2)h1->buf0  ph5: A(T+2)h1->buf0
//   ph6: B(T+3)h0->buf1  ph7: A(T+3)h0->buf1
// Queue at end-ph3 = 12 loads; VMW(4) completes oldest 8 = tile T+1 fully
// landed (B(T+2)h0 + A(T+2)h0 stay in flight).  End-ph7 symmetric for T+2.
// Every staging target's previous readers retired >=1 barrier earlier
// (verified half-by-half); publish-dependent reads (ph4 / next-ph0) sit
// below the VMW fence so the compiler cannot hoist them.

template<int K>
__global__ __launch_bounds__(512, 2) void k_gemm_g1(const unsigned short* __restrict__ A,
                                                    const unsigned short* __restrict__ Bm,
                                                    unsigned short* __restrict__ hallO,
                                                    unsigned short* __restrict__ csO,
                                                    const float* __restrict__ x2,
                                                    const float* __restrict__ c2,
                                                    const float* __restrict__ bias1,
                                                    const float* __restrict__ bias2,
                                                    unsigned int* __restrict__ dmin) {
    __shared__ unsigned short As[2][256 * 64];
    __shared__ unsigned short Bs[2][256 * 64];
    constexpr int nt = K / 64;

    const int tid = threadIdx.x, lane = tid & 63, w = tid >> 6;
    const int wm = w >> 2, wn = w & 3;
    const int lr = lane & 15, lq = lane >> 4;
    const int e2 = (lr >> 2) & 1, e3 = lr & 3;

    const int nbn2 = (gridDim.x >> 5) >> 1;
    const int xcd = blockIdx.x & 7, idx = blockIdx.x >> 3;
    const int bm = (xcd & 3) * 8 + (idx & 7);
    const int bn = (xcd >> 2) * nbn2 + (idx >> 3);
    const size_t m0 = (size_t)bm * 256, n0 = (size_t)bn * 256;

    f32x4 acc[8][4] = {};

    const char* pA0 = (const char*)As + wm * 16384 + lr * 128 + (lq ^ e3) * 16 + (0 ^ e2) * 64;
    const char* pA1 = (const char*)As + wm * 16384 + lr * 128 + (lq ^ e3) * 16 + (1 ^ e2) * 64;
    const char* pB0 = (const char*)Bs + wn * 8192 + lr * 128 + (lq ^ e3) * 16 + (0 ^ e2) * 64;
    const char* pB1 = (const char*)Bs + wn * 8192 + lr * 128 + (lq ^ e3) * 16 + (1 ^ e2) * 64;

    const int fsw = (tid >> 3) & 7;
    const unsigned short* gAsrc = A + m0 * K + (size_t)(tid >> 3) * K + ((tid & 7) ^ fsw) * 8;
    const unsigned short* gBsrc = Bm + n0 * K + (size_t)(tid >> 3) * K + ((tid & 7) ^ fsw) * 8;
    char* stA0 = (char*)As + tid * 16;            // buf0
    char* stA1 = (char*)As + 32768 + tid * 16;    // buf1
    char* stB0 = (char*)Bs + tid * 16;
    char* stB1 = (char*)Bs + 32768 + tid * 16;
    const unsigned short* gA_run = gAsrc;
    const unsigned short* gB_run = gBsrc;

    // prologue: B0h0,B0h1,A0h0,A0h1 -> buf0; B1h0,A1h0 -> buf1 (12 loads)
    STG_HALF(gBsrc, 0, stB0);
    STG_HALF(gBsrc, 1, stB0);
    STG_HALF(gAsrc, 0, stA0);
    STG_HALF(gAsrc, 1, stA0);
    STG_HALF(gBsrc + 64, 0, stB1);
    STG_HALF(gAsrc + 64, 0, stA1);
    VMW(4);     // tile 0 fully landed; B1h0,A1h0 in flight
    BAR();

    bf16x8 a0[8], a1[8], b0[4], b1[4];

    for (int it = 0; it < nt / 2; ++it) {
        // ================= tile T (buf0) =================
        // ph0
        LDA8O(a0, 0, 0);
        LDB4O(b0, 0, 0);
        STG_HALF(gB_run + 64, 1, stB1);      // B(T+1)h1
        BAR();
        PRIO1(); MFMA16(a0, b0, 0, 0); PRIO0();
        BAR();
        // ph1
        LDB4O(b1, 1, 0);
        STG_HALF(gA_run + 64, 1, stA1);      // A(T+1)h1
        BAR();
        PRIO1(); MFMA16(a0, b1, 0, 2); PRIO0();
        BAR();
        // ph2
        LDA8O(a1, 1, 0);
        STG_HALF(gB_run + 128, 0, stB0);     // B(T+2)h0
        BAR();
        PRIO1(); MFMA16(a1, b1, 4, 2); PRIO0();
        BAR();
        // ph3
        STG_HALF(gA_run + 128, 0, stA0);     // A(T+2)h0
        BAR();
        PRIO1(); MFMA16(a1, b0, 4, 0); PRIO0();
        VMW(4);                               // tile T+1 fully landed
        BAR();

        // ================= tile T+1 (buf1) =================
        // ph4
        LDA8O(a0, 0, 32768);
        LDB4O(b0, 0, 32768);
        STG_HALF(gB_run + 128, 1, stB0);     // B(T+2)h1
        BAR();
        PRIO1(); MFMA16(a0, b0, 0, 0); PRIO0();
        BAR();
        // ph5
        LDB4O(b1, 1, 32768);
        STG_HALF(gA_run + 128, 1, stA0);     // A(T+2)h1
        BAR();
        PRIO1(); MFMA16(a0, b1, 0, 2); PRIO0();
        BAR();
        // ph6
        LDA8O(a1, 1, 32768);
        STG_HALF(gB_run + 192, 0, stB1);     // B(T+3)h0
        BAR();
        PRIO1(); MFMA16(a1, b1, 4, 2); PRIO0();
        BAR();
        // ph7
        STG_HALF(gA_run + 192, 0, stA1);     // A(T+3)h0
        BAR();
        PRIO1(); MFMA16(a1, b0, 4, 0); PRIO0();
        VMW(4);                               // tile T+2 fully landed
        BAR();

        gA_run += 128; gB_run += 128;
    }
    VMW(0);

    // ---- epilogue ----
    const int segc = (n0 >= 2048) ? 2 : (int)(n0 >> 10);

    #pragma unroll
    for (int mi = 0; mi < 8; mi++) {
        #pragma unroll
        for (int j = 0; j < 4; j++) {
            const int row = (int)m0 + wm * 128 + mi * 16 + lq * 4 + j;
            if (segc == 0) {
                float x2r = x2[row];
                float mn = 1e30f;
                #pragma unroll
                for (int ni = 0; ni < 4; ni++) {
                    int col = (int)n0 + wn * 64 + ni * 16 + lr;
                    float d = fmaxf(x2r - 2.0f * acc[mi][ni][j] + c2[col], 0.0f);
                    if (col >= C_) d = 1e30f;
                    mn = fminf(mn, d);
                }
                mn = fminf(mn, __shfl_xor(mn, 1));
                mn = fminf(mn, __shfl_xor(mn, 2));
                mn = fminf(mn, __shfl_xor(mn, 4));
                mn = fminf(mn, __shfl_xor(mn, 8));
                if (lr == 0) atomicMin(dmin + row, __float_as_uint(mn));
            } else if (segc == 1) {
                #pragma unroll
                for (int ni = 0; ni < 4; ni++) {
                    int col = (int)n0 + wn * 64 + ni * 16 + lr;
                    int c = col - 1024;
                    hallO[(size_t)row * 1024 + c] = f2bf(acc[mi][ni][j] + (c < C_ ? bias1[c] : 0.0f));
                }
            } else {
                #pragma unroll
                for (int ni = 0; ni < 4; ni++) {
                    int col = (int)n0 + wn * 64 + ni * 16 + lr;
                    int c = col - 2048;
                    csO[(size_t)row * F_ + c] = f2bf(fast_tanh(acc[mi][ni][j] + bias2[c]));
                }
            }
        }
    }
}

// ---------- 128x256 variant (R6 proven schedule), EPI 2 = G3, 3 = G2 ----------

#define STG_A128(gp, half, ldsbase)                                             \
    async16((gp) + ((half) * 64) * (size_t)K, (ldsbase) + (half) * 8192);

#define LDA4O(dst, kk, off)                                                     \
    _Pragma("unroll")                                                           \
    for (int i_ = 0; i_ < 4; i_++)                                              \
        dst[i_] = *(const bf16x8*)(((kk) ? pA1 : pA0) + (off) + i_ * 2048);

#define MFMA8K(av, bv, ni0, ks)                                                 \
    _Pragma("unroll")                                                           \
    for (int i_ = 0; i_ < 4; i_++)                                              \
        _Pragma("unroll")                                                       \
        for (int j_ = 0; j_ < 2; j_++)                                          \
            acc[i_][(ni0) + j_] = __builtin_amdgcn_mfma_f32_16x16x32_bf16(      \
                av[i_], bv[j_ * 2 + (ks)], acc[i_][(ni0) + j_], 0, 0, 0);

template<int EPI, int K>
__global__ __launch_bounds__(512, 2) void k_gemm128(const unsigned short* __restrict__ A,
                                                    const unsigned short* __restrict__ Bm,
                                                    float* __restrict__ O0,
                                                    unsigned short* __restrict__ O2,
                                                    const unsigned short* __restrict__ csrc,
                                                    const unsigned short* __restrict__ xsrcb,
                                                    const float* __restrict__ reach,
                                                    float* __restrict__ ssum) {
    __shared__ unsigned short As[2][128 * 64];   // 2 x 16 KiB
    __shared__ unsigned short Bs[2][256 * 64];   // 2 x 32 KiB
    constexpr int nt = K / 64;
    constexpr int nbn = (EPI == 3) ? 8 : 4;      // N-tiles (G2: N=2048, G3: N=1024)

    const int tid = threadIdx.x, lane = tid & 63, w = tid >> 6;
    const int wm = w >> 2, wn = w & 3;
    const int lr = lane & 15, lq = lane >> 4;
    const int e2 = (lr >> 2) & 1, e3 = lr & 3;

    // grid = 64*nbn blocks; per-XCD: 8 contiguous bm x all bn (bijective)
    const int xcd = blockIdx.x & 7, idx = blockIdx.x >> 3;
    const int bm = xcd * 8 + idx / nbn;
    const int bn = idx % nbn;
    const size_t m0 = (size_t)bm * 128, n0 = (size_t)bn * 256;

    f32x4 acc[4][4] = {};

    const char* pA0 = (const char*)As + wm * 8192 + lr * 128 + (lq ^ e3) * 16 + (0 ^ e2) * 64;
    const char* pA1 = (const char*)As + wm * 8192 + lr * 128 + (lq ^ e3) * 16 + (1 ^ e2) * 64;
    const char* pB0 = (const char*)Bs + wn * 8192 + lr * 128 + (lq ^ e3) * 16 + (0 ^ e2) * 64;
    const char* pB1 = (const char*)Bs + wn * 8192 + lr * 128 + (lq ^ e3) * 16 + (1 ^ e2) * 64;

    const int fsw = (tid >> 3) & 7;
    const unsigned short* gAsrc = A + m0 * K + (size_t)(tid >> 3) * K + ((tid & 7) ^ fsw) * 8;
    const unsigned short* gBsrc = Bm + n0 * K + (size_t)(tid >> 3) * K + ((tid & 7) ^ fsw) * 8;
    char* stA_run = (char*)As + 16384 + tid * 16;   // A(t+1) -> other buffer
    char* stB_run = (char*)Bs + tid * 16;           // B(t+2) -> same-parity buffer
    const unsigned short* gA_run = gAsrc + 64;
    const unsigned short* gB_run = gBsrc + 128;
    int dirA = 16384, dirB = 32768;

    // prologue: A(0) (2 loads), B(0) (4), B(1) (4); VMW(4) => A(0)+B(0) landed
    STG_A128(gAsrc, 0, (char*)As + tid * 16);
    STG_A128(gAsrc, 1, (char*)As + tid * 16);
    STG_HALF(gBsrc, 0, (char*)Bs + tid * 16);
    STG_HALF(gBsrc, 1, (char*)Bs + tid * 16);
    STG_HALF(gBsrc + 64, 0, (char*)Bs + 32768 + tid * 16);
    STG_HALF(gBsrc + 64, 1, (char*)Bs + 32768 + tid * 16);
    VMW(4);
    BAR();

    bf16x8 ak0[4], ak1[4], b0[4], b1[4];
    LDA4O(ak0, 0, 0);
    LDB4O(b0, 0, 0);

    for (int t = 0; t < nt; ++t) {
        // ---- phase 0: stage A(t+1) both halves ----
        STG_A128(gA_run, 0, stA_run);
        STG_A128(gA_run, 1, stA_run);
        PRIO1();
        LDB4O(b1, 1, 0);
        MFMA8K(ak0, b0, 0, 0);
        PRIO0();

        // ---- phase 1 ----
        PRIO1();
        LDA4O(ak1, 1, 0);
        MFMA8K(ak0, b1, 2, 0);
        PRIO0();
        BAR();

        // ---- phase 2: stage B(t+2) both halves ----
        STG_HALF(gB_run, 0, stB_run);
        STG_HALF(gB_run, 1, stB_run);
        PRIO1();
        MFMA8K(ak1, b0, 0, 1);
        PRIO0();
        VMW(4);
        BAR();

        // ---- phase 3 ----
        PRIO1();
        LDA4O(ak0, 0, dirA);
        LDB4O(b0, 0, dirB);
        MFMA8K(ak1, b1, 2, 1);
        PRIO0();

        gA_run += 64; gB_run += 64;
        pA0 += dirA; pA1 += dirA; pB0 += dirB; pB1 += dirB;
        stA_run -= dirA; stB_run += dirB;
        dirA = -dirA; dirB = -dirB;
    }
    VMW(0);

    // ---- epilogue ----
    #pragma unroll
    for (int mi = 0; mi < 4; mi++) {
        #pragma unroll
        for (int j = 0; j < 4; j++) {
            const int row = (int)m0 + wm * 64 + mi * 16 + lq * 4 + j;
            if (EPI == 2) {
                float sc = 1.0f / (1.0f + sqrtf(ssum[row]));
                #pragma unroll
                for (int ni = 0; ni < 4; ni++) {
                    int col = (int)n0 + wn * 64 + ni * 16 + lr;
                    if (col < C_) O0[(size_t)row * C_ + col] = acc[mi][ni][j] * sc;
                }
            } else { // EPI == 3: inf = cs*mem; xo = reach*(x+inf); ssum += xo^2
                float r = reach[row];
                float ssp = 0.0f;
                #pragma unroll
                for (int ni = 0; ni < 4; ni++) {
                    int col = (int)n0 + wn * 64 + ni * 16 + lr;
                    size_t id = (size_t)row * F_ + col;
                    float mem = acc[mi][ni][j];
                    float inf = bf2f(csrc[id]) * mem;
                    float xo = r * (bf2f(xsrcb[id]) + inf);
                    O0[id] = inf;            // out_infused (f32)
                    O2[id] = f2bf(xo);       // xo_bf for G3 (same buffer as xsrcb; RAW per-thread)
                    ssp += xo * xo;
                }
                ssp += __shfl_xor(ssp, 1);
                ssp += __shfl_xor(ssp, 2);
                ssp += __shfl_xor(ssp, 4);
                ssp += __shfl_xor(ssp, 8);
                if (lr == 0) atomicAdd(ssum + row, ssp);
            }
        }
    }
}

// ---------- softmax (bf16 in) + reach finalize ----------

__global__ __launch_bounds__(256) void k_softmax(const unsigned short* __restrict__ L,
                                                 unsigned short* __restrict__ vm,
                                                 const unsigned int* __restrict__ dmin,
                                                 float* __restrict__ reach) {
    int row = blockIdx.x, t = threadIdx.x;
    float v[4]; float mx = -1e30f;
    #pragma unroll
    for (int i = 0; i < 4; i++) {
        int col = t + i * 256;
        float val = (col < C_) ? bf2f(L[(size_t)row * CP + col]) : -1e30f;
        v[i] = val; mx = fmaxf(mx, val);
    }
    mx = blockReduce<1>(mx);
    float s = 0.f;
    #pragma unroll
    for (int i = 0; i < 4; i++) {
        int col = t + i * 256;
        v[i] = (col < C_) ? __expf(v[i] - mx) : 0.0f;
        s += v[i];
    }
    s = blockReduce<0>(s);
    float inv = 1.0f / s;
    #pragma unroll
    for (int i = 0; i < 4; i++) vm[(size_t)row * CP + t + i * 256] = f2bf(v[i] * inv);
    if (t == 0) {
        float m = __uint_as_float(dmin[row]);
        reach[row] = 10.0f / (sqrtf(m) + 1e-5f);
    }
}

// ---------- host ----------

extern "C" void kernel_launch(void* const* d_in, const int* in_sizes, int n_in,
                              void* d_out, int out_size, void* d_ws, size_t ws_size,
                              hipStream_t stream) {
    const float* x     = (const float*)d_in[0];
    const float* cent  = (const float*)d_in[1];
    const float* Whall = (const float*)d_in[2];
    const float* bhall = (const float*)d_in[3];
    const float* Wsel  = (const float*)d_in[4];
    const float* bsel  = (const float*)d_in[5];
    const float* Wcos  = (const float*)d_in[6];

    float* out_logits  = (float*)d_out;
    float* out_direct  = out_logits + (size_t)B_ * C_;
    float* out_infused = out_direct + (size_t)B_ * F_;

    char* ws = (char*)d_ws;
    unsigned short* x_bf    = (unsigned short*)(ws);                 // 33.5 MB [8192][2048]
    unsigned short* Bcat    = (unsigned short*)(ws + 33554432);      // 16 MB  [4096][2048]
    unsigned short* centT   = (unsigned short*)(ws + 50331648);      // 4 MB   [2048][1024]
    unsigned short* wcos_bf = (unsigned short*)(ws + 54525952);      // 4 MB   [1024][2048]
    unsigned short* cs_bf   = (unsigned short*)(ws + 58720256);      // 33.5 MB [8192][2048]
    float* x2    = (float*)(ws + 92274688);
    float* c2    = (float*)(ws + 92307456);
    float* reach = (float*)(ws + 92311552);
    unsigned int* dmin = (unsigned int*)(ws + 92344320);
    float* ssum  = (float*)(ws + 92377088);

    // scratch aliased onto output regions (strictly stream-ordered before final writes)
    unsigned short* hall_bf = (unsigned short*)(out_infused + (size_t)B_ * 1024); // [8192][1024] bf16
    unsigned short* vm_bf = (unsigned short*)out_logits;   // [8192][1024] bf16, dead after G2
    unsigned short* xo_bf = x_bf;                          // xo overwrites x_bf in G2 epilogue

    k_prep<<<13312, 256, 0, stream>>>(x, cent, Whall, Wsel, Wcos,
                                      x_bf, x2, out_direct, dmin, ssum,
                                      Bcat, centT, c2, wcos_bf);

    // G1: dmin | hall logits (bf16) | concept selector (M=8192, N=4096, K=2048)
    k_gemm_g1<F_><<<dim3(512), 512, 0, stream>>>(
        x_bf, Bcat, hall_bf, cs_bf, x2, c2, bhall, bsel, dmin);

    k_softmax<<<B_, 256, 0, stream>>>(hall_bf, vm_bf, dmin, reach);

    // G2: memory_feature + fused infuse/norm (M=8192, N=2048, K=1024) -> 512 blocks
    k_gemm128<3, CP><<<dim3(512), 512, 0, stream>>>(
        vm_bf, centT, out_infused, xo_bf, cs_bf, x_bf, reach, ssum);

    // G3: logits = (xo @ (16*ew)^T) * 1/(1+||xo||) (M=8192, N=1024, K=2048) -> 256 blocks
    k_gemm128<2, F_><<<dim3(256), 512, 0, stream>>>(
        xo_bf, wcos_bf, out_logits, nullptr, nullptr, nullptr, nullptr, ssum);

    (void)in_sizes; (void)n_in; (void)out_size; (void)ws_size;
}

// Round 9
// 308.896 us; speedup vs baseline: 1.0673x; 1.0673x over previous
//
#include <hip/hip_runtime.h>
#include <hip/hip_bf16.h>

#define B_ 8192
#define F_ 2048
#define C_ 1000
#define CP 1024

typedef __attribute__((ext_vector_type(4))) float f32x4;
typedef __attribute__((ext_vector_type(8))) short bf16x8;
typedef __attribute__((ext_vector_type(8))) unsigned short u16x8;

__device__ __forceinline__ unsigned short f2bf(float f) {
    union { float f; unsigned int u; } x; x.f = f;
    unsigned int r = x.u + 0x7fffu + ((x.u >> 16) & 1u);
    return (unsigned short)(r >> 16);
}
__device__ __forceinline__ float bf2f(unsigned short h) {
    union { unsigned int u; float f; } x; x.u = ((unsigned int)h) << 16; return x.f;
}

template<int OP>
__device__ __forceinline__ float blockReduce(float v) {
    __shared__ float s[4];
    #pragma unroll
    for (int o = 32; o; o >>= 1) {
        float u = __shfl_down(v, o);
        v = (OP == 0) ? v + u : (OP == 1) ? fmaxf(v, u) : fminf(v, u);
    }
    __syncthreads();
    if ((threadIdx.x & 63) == 0) s[threadIdx.x >> 6] = v;
    __syncthreads();
    float r = s[0];
    #pragma unroll
    for (int i = 1; i < 4; i++) r = (OP == 0) ? r + s[i] : (OP == 1) ? fmaxf(r, s[i]) : fminf(r, s[i]);
    return r;
}

__device__ __forceinline__ void async16(const void* g, void* l) {
    __builtin_amdgcn_global_load_lds(
        (const __attribute__((address_space(1))) void*)g,
        (__attribute__((address_space(3))) void*)l, 16, 0, 0);
}

// ---------- merged prep (unchanged) ----------

__global__ __launch_bounds__(256) void k_prep(const float* __restrict__ x,
                                              const float* __restrict__ cent,
                                              const float* __restrict__ Whall,
                                              const float* __restrict__ Wsel,
                                              const float* __restrict__ Wcos,
                                              unsigned short* __restrict__ xbf,
                                              float* __restrict__ x2,
                                              float* __restrict__ direct,
                                              unsigned int* __restrict__ dmin,
                                              float* __restrict__ ssum,
                                              unsigned short* __restrict__ Bcat,
                                              unsigned short* __restrict__ cT,
                                              float* __restrict__ c2,
                                              unsigned short* __restrict__ wcos_bf) {
    const int bid = blockIdx.x, t = threadIdx.x;

    if (bid < 8192) {
        int row = bid;
        size_t base = (size_t)row * F_ + t * 8;
        float4 a = *(const float4*)(x + base);
        float4 b = *(const float4*)(x + base + 4);
        float v[8] = {a.x, a.y, a.z, a.w, b.x, b.y, b.z, b.w};
        u16x8 u; float ss = 0.f;
        #pragma unroll
        for (int j = 0; j < 8; j++) { ss += v[j] * v[j]; u[j] = f2bf(v[j]); }
        *(u16x8*)(xbf + base) = u;
        *(float4*)(direct + base) = a;
        *(float4*)(direct + base + 4) = b;
        ss = blockReduce<0>(ss);
        if (t == 0) { x2[row] = ss; dmin[row] = 0x7f7f7f7fu; ssum[row] = 0.0f; }
    } else if (bid < 9216) {
        int row = bid - 8192;
        size_t base = (size_t)row * F_ + t * 8;
        if (row < C_) {
            float4 a = *(const float4*)(cent + base);
            float4 b = *(const float4*)(cent + base + 4);
            float v[8] = {a.x, a.y, a.z, a.w, b.x, b.y, b.z, b.w};
            u16x8 u; float ss = 0.f;
            #pragma unroll
            for (int j = 0; j < 8; j++) { ss += v[j] * v[j]; u[j] = f2bf(v[j]); }
            *(u16x8*)(Bcat + base) = u;
            #pragma unroll
            for (int j = 0; j < 8; j++) cT[(size_t)(t * 8 + j) * CP + row] = u[j];
            ss = blockReduce<0>(ss);
            if (t == 0) c2[row] = ss;
        } else {
            u16x8 u;
            #pragma unroll
            for (int j = 0; j < 8; j++) u[j] = 0;
            *(u16x8*)(Bcat + base) = u;
            #pragma unroll
            for (int j = 0; j < 8; j++) cT[(size_t)(t * 8 + j) * CP + row] = 0;
            if (t == 0) c2[row] = 0.f;
        }
    } else if (bid < 10240) {
        int row = bid - 9216;
        size_t base = (size_t)row * F_ + t * 8;
        u16x8 u;
        if (row < C_) {
            float4 a = *(const float4*)(Whall + base);
            float4 b = *(const float4*)(Whall + base + 4);
            float v[8] = {a.x, a.y, a.z, a.w, b.x, b.y, b.z, b.w};
            #pragma unroll
            for (int j = 0; j < 8; j++) u[j] = f2bf(v[j]);
        } else {
            #pragma unroll
            for (int j = 0; j < 8; j++) u[j] = 0;
        }
        *(u16x8*)(Bcat + (size_t)1024 * F_ + base) = u;
    } else if (bid < 12288) {
        int row = bid - 10240;
        size_t base = (size_t)row * F_ + t * 8;
        float4 a = *(const float4*)(Wsel + base);
        float4 b = *(const float4*)(Wsel + base + 4);
        float v[8] = {a.x, a.y, a.z, a.w, b.x, b.y, b.z, b.w};
        u16x8 u;
        #pragma unroll
        for (int j = 0; j < 8; j++) u[j] = f2bf(v[j]);
        *(u16x8*)(Bcat + (size_t)2048 * F_ + base) = u;
    } else {
        int row = bid - 12288;
        size_t base = (size_t)row * F_ + t * 8;
        u16x8 u;
        if (row < C_) {
            float4 a = *(const float4*)(Wcos + base);
            float4 b = *(const float4*)(Wcos + base + 4);
            float v[8] = {a.x, a.y, a.z, a.w, b.x, b.y, b.z, b.w};
            float ss = 0.f;
            #pragma unroll
            for (int j = 0; j < 8; j++) ss += v[j] * v[j];
            ss = blockReduce<0>(ss);
            float sc = 16.0f / sqrtf(ss);
            #pragma unroll
            for (int j = 0; j < 8; j++) u[j] = f2bf(v[j] * sc);
        } else {
            #pragma unroll
            for (int j = 0; j < 8; j++) u[j] = 0;
        }
        *(u16x8*)(wcos_bf + base) = u;
    }
}

// ---------- shared GEMM machinery (R2/R6 proven 4-phase skeleton) ----------
//   ph0: MFMA(a0,b0)  | prefetch b1  | stage A(t+1)h0
//   ph1: MFMA(a0,b1)  | prefetch a1  | stage A(t+1)h1   -> BAR (staging WAR)
//   ph2: MFMA(a1,b0)  |              | stage B(t+2)h0   -> VMW(n)+BAR (publish)
//   ph3: MFMA(a1,b1)  | prefetch a0',b0' (NEXT buffer)  | stage B(t+2)h1
// VMW(n) completes exactly A(t+1)+B(t+1), leaving B(t+2)h0 in flight.

#define BAR() __builtin_amdgcn_s_barrier()
#define VMW(N) asm volatile("s_waitcnt vmcnt(" #N ")" ::: "memory")
#define PRIO1() __builtin_amdgcn_s_setprio(1)
#define PRIO0() __builtin_amdgcn_s_setprio(0)

#define LDA8O(dst, mh, off)                                                     \
    _Pragma("unroll")                                                           \
    for (int i_ = 0; i_ < 4; i_++) {                                            \
        dst[i_ * 2 + 0] = *(const bf16x8*)(pA0 + (off) + (mh) * 8192 + i_ * 2048); \
        dst[i_ * 2 + 1] = *(const bf16x8*)(pA1 + (off) + (mh) * 8192 + i_ * 2048); \
    }

#define LDB4O(dst, nh, off)                                                     \
    _Pragma("unroll")                                                           \
    for (int i_ = 0; i_ < 2; i_++) {                                            \
        dst[i_ * 2 + 0] = *(const bf16x8*)(pB0 + (off) + (nh) * 4096 + i_ * 2048); \
        dst[i_ * 2 + 1] = *(const bf16x8*)(pB1 + (off) + (nh) * 4096 + i_ * 2048); \
    }

#define STG_HALF(gp, half, ldsbase)                                             \
    _Pragma("unroll")                                                           \
    for (int i_ = 0; i_ < 2; i_++)                                              \
        async16((gp) + ((half) * 128 + i_ * 64) * (size_t)K,                    \
                (ldsbase) + (half) * 16384 + i_ * 8192);

#define MFMA16(a, b, mi0, ni0)                                                  \
    _Pragma("unroll")                                                           \
    for (int ks_ = 0; ks_ < 2; ks_++)                                           \
        _Pragma("unroll")                                                       \
        for (int i_ = 0; i_ < 4; i_++)                                          \
            _Pragma("unroll")                                                   \
            for (int j_ = 0; j_ < 2; j_++)                                      \
                acc[(mi0) + i_][(ni0) + j_] = __builtin_amdgcn_mfma_f32_16x16x32_bf16( \
                    a[i_ * 2 + ks_], b[j_ * 2 + ks_], acc[(mi0) + i_][(ni0) + j_], 0, 0, 0);

__device__ __forceinline__ float fast_tanh(float v) {
    float t = __expf(v + v);
    return (t - 1.0f) / (t + 1.0f);
}

// ---------- G1: 256x256 GEMM (R6 verbatim), fused epilogue ----------

template<int K>
__global__ __launch_bounds__(512, 2) void k_gemm_g1(const unsigned short* __restrict__ A,
                                                    const unsigned short* __restrict__ Bm,
                                                    unsigned short* __restrict__ hallO,
                                                    unsigned short* __restrict__ csO,
                                                    const float* __restrict__ x2,
                                                    const float* __restrict__ c2,
                                                    const float* __restrict__ bias1,
                                                    const float* __restrict__ bias2,
                                                    unsigned int* __restrict__ dmin) {
    __shared__ unsigned short As[2][256 * 64];
    __shared__ unsigned short Bs[2][256 * 64];
    constexpr int nt = K / 64;

    const int tid = threadIdx.x, lane = tid & 63, w = tid >> 6;
    const int wm = w >> 2, wn = w & 3;
    const int lr = lane & 15, lq = lane >> 4;
    const int e2 = (lr >> 2) & 1, e3 = lr & 3;

    const int nbn2 = (gridDim.x >> 5) >> 1;
    const int xcd = blockIdx.x & 7, idx = blockIdx.x >> 3;
    const int bm = (xcd & 3) * 8 + (idx & 7);
    const int bn = (xcd >> 2) * nbn2 + (idx >> 3);
    const size_t m0 = (size_t)bm * 256, n0 = (size_t)bn * 256;

    f32x4 acc[8][4] = {};

    const char* pA0 = (const char*)As + wm * 16384 + lr * 128 + (lq ^ e3) * 16 + (0 ^ e2) * 64;
    const char* pA1 = (const char*)As + wm * 16384 + lr * 128 + (lq ^ e3) * 16 + (1 ^ e2) * 64;
    const char* pB0 = (const char*)Bs + wn * 8192 + lr * 128 + (lq ^ e3) * 16 + (0 ^ e2) * 64;
    const char* pB1 = (const char*)Bs + wn * 8192 + lr * 128 + (lq ^ e3) * 16 + (1 ^ e2) * 64;

    const int fsw = (tid >> 3) & 7;
    const unsigned short* gAsrc = A + m0 * K + (size_t)(tid >> 3) * K + ((tid & 7) ^ fsw) * 8;
    const unsigned short* gBsrc = Bm + n0 * K + (size_t)(tid >> 3) * K + ((tid & 7) ^ fsw) * 8;
    char* stA_run = (char*)As + 32768 + tid * 16;
    char* stB_run = (char*)Bs + tid * 16;
    const unsigned short* gA_run = gAsrc + 64;
    const unsigned short* gB_run = gBsrc + 128;
    int dir = 32768;

    STG_HALF(gAsrc, 0, (char*)As + tid * 16);
    STG_HALF(gAsrc, 1, (char*)As + tid * 16);
    STG_HALF(gBsrc, 0, (char*)Bs + tid * 16);
    STG_HALF(gBsrc, 1, (char*)Bs + tid * 16);
    STG_HALF(gBsrc + 64, 0, (char*)Bs + 32768 + tid * 16);
    STG_HALF(gBsrc + 64, 1, (char*)Bs + 32768 + tid * 16);
    VMW(4);
    BAR();

    bf16x8 a0[8], a1[8], b0[4], b1[4];
    LDA8O(a0, 0, 0);
    LDB4O(b0, 0, 0);

    for (int t = 0; t < nt; ++t) {
        // ---- phase 0 ----
        STG_HALF(gA_run, 0, stA_run);
        PRIO1();
        LDB4O(b1, 1, 0);
        MFMA16(a0, b0, 0, 0);
        PRIO0();

        // ---- phase 1 ----
        STG_HALF(gA_run, 1, stA_run);
        PRIO1();
        LDA8O(a1, 1, 0);
        MFMA16(a0, b1, 0, 2);
        PRIO0();
        BAR();   // staging-WAR barrier

        // ---- phase 2 ----
        STG_HALF(gB_run, 0, stB_run);
        PRIO1();
        MFMA16(a1, b0, 4, 0);
        PRIO0();
        VMW(2);
        BAR();   // publish barrier: A(t+1)+B(t+1) visible

        // ---- phase 3 ----
        STG_HALF(gB_run, 1, stB_run);
        PRIO1();
        LDA8O(a0, 0, dir);
        LDB4O(b0, 0, dir);
        MFMA16(a1, b1, 4, 2);
        PRIO0();

        gA_run += 64; gB_run += 64;
        pA0 += dir; pA1 += dir; pB0 += dir; pB1 += dir;
        stB_run += dir; stA_run -= dir;
        dir = -dir;
    }
    VMW(0);

    // ---- epilogue ----
    const int segc = (n0 >= 2048) ? 2 : (int)(n0 >> 10);

    #pragma unroll
    for (int mi = 0; mi < 8; mi++) {
        #pragma unroll
        for (int j = 0; j < 4; j++) {
            const int row = (int)m0 + wm * 128 + mi * 16 + lq * 4 + j;
            if (segc == 0) {
                float x2r = x2[row];
                float mn = 1e30f;
                #pragma unroll
                for (int ni = 0; ni < 4; ni++) {
                    int col = (int)n0 + wn * 64 + ni * 16 + lr;
                    float d = fmaxf(x2r - 2.0f * acc[mi][ni][j] + c2[col], 0.0f);
                    if (col >= C_) d = 1e30f;
                    mn = fminf(mn, d);
                }
                mn = fminf(mn, __shfl_xor(mn, 1));
                mn = fminf(mn, __shfl_xor(mn, 2));
                mn = fminf(mn, __shfl_xor(mn, 4));
                mn = fminf(mn, __shfl_xor(mn, 8));
                if (lr == 0) atomicMin(dmin + row, __float_as_uint(mn));
            } else if (segc == 1) {
                #pragma unroll
                for (int ni = 0; ni < 4; ni++) {
                    int col = (int)n0 + wn * 64 + ni * 16 + lr;
                    int c = col - 1024;
                    hallO[(size_t)row * 1024 + c] = f2bf(acc[mi][ni][j] + (c < C_ ? bias1[c] : 0.0f));
                }
            } else {
                #pragma unroll
                for (int ni = 0; ni < 4; ni++) {
                    int col = (int)n0 + wn * 64 + ni * 16 + lr;
                    int c = col - 2048;
                    csO[(size_t)row * F_ + c] = f2bf(fast_tanh(acc[mi][ni][j] + bias2[c]));
                }
            }
        }
    }
}

// ---------- 128x128 variant: 64 KiB LDS -> 2 blocks/CU, same 4-phase skeleton ----------
// 8 waves as 4M x 2N; per-wave 32 rows x 64 cols, acc[2][4], 16 MFMA/tile.
// A/B halves = 64 rows = 1 async16/thread. Gate derivation: queue at end-ph2 =
// [B(t+1)h0 (in flight from prev gate), B(t+1)h1 @ph3(t-1), A(t+1)h0 @ph0,
//  A(t+1)h1 @ph1, B(t+2)h0 @ph2] = 5 -> VMW(1) completes oldest 4 = exactly
// tile t+1, leaving B(t+2)h0 in flight. Prologue 6 loads -> VMW(2) = tile 0.

#define STG_64(gp, half, ldsbase)                                               \
    async16((gp) + ((half) * 64) * (size_t)K, (ldsbase) + (half) * 8192);

#define LDA2O(dst, kk, off)                                                     \
    _Pragma("unroll")                                                           \
    for (int i_ = 0; i_ < 2; i_++)                                              \
        dst[i_] = *(const bf16x8*)(((kk) ? pA1 : pA0) + (off) + i_ * 2048);

#define MFMA4K(av, bv, ni0, ks)                                                 \
    _Pragma("unroll")                                                           \
    for (int i_ = 0; i_ < 2; i_++)                                              \
        _Pragma("unroll")                                                       \
        for (int j_ = 0; j_ < 2; j_++)                                          \
            acc[i_][(ni0) + j_] = __builtin_amdgcn_mfma_f32_16x16x32_bf16(      \
                av[i_], bv[j_ * 2 + (ks)], acc[i_][(ni0) + j_], 0, 0, 0);

template<int EPI, int K>
__global__ __launch_bounds__(512, 4) void k_gemmS(const unsigned short* __restrict__ A,
                                                  const unsigned short* __restrict__ Bm,
                                                  float* __restrict__ O0,
                                                  unsigned short* __restrict__ O2,
                                                  const unsigned short* __restrict__ csrc,
                                                  const unsigned short* __restrict__ xsrcb,
                                                  const float* __restrict__ reach,
                                                  float* __restrict__ ssum) {
    __shared__ unsigned short As[2][128 * 64];   // 2 x 16 KiB
    __shared__ unsigned short Bs[2][128 * 64];   // 2 x 16 KiB -> 64 KiB total
    constexpr int nt = K / 64;
    constexpr int nbn = (EPI == 3) ? 16 : 8;     // N/128 (G2: 2048, G3: 1024)

    const int tid = threadIdx.x, lane = tid & 63, w = tid >> 6;
    const int wm = w >> 1, wn = w & 1;           // 4M x 2N waves
    const int lr = lane & 15, lq = lane >> 4;
    const int e2 = (lr >> 2) & 1, e3 = lr & 3;

    // grid = 64*nbn blocks; per-XCD: 8 contiguous bm x all bn (bijective)
    const int xcd = blockIdx.x & 7, idx = blockIdx.x >> 3;
    const int bm = xcd * 8 + idx / nbn;
    const int bn = idx % nbn;
    const size_t m0 = (size_t)bm * 128, n0 = (size_t)bn * 128;

    f32x4 acc[2][4] = {};

    const char* pA0 = (const char*)As + wm * 4096 + lr * 128 + (lq ^ e3) * 16 + (0 ^ e2) * 64;
    const char* pA1 = (const char*)As + wm * 4096 + lr * 128 + (lq ^ e3) * 16 + (1 ^ e2) * 64;
    const char* pB0 = (const char*)Bs + wn * 8192 + lr * 128 + (lq ^ e3) * 16 + (0 ^ e2) * 64;
    const char* pB1 = (const char*)Bs + wn * 8192 + lr * 128 + (lq ^ e3) * 16 + (1 ^ e2) * 64;

    const int fsw = (tid >> 3) & 7;
    const unsigned short* gAsrc = A + m0 * K + (size_t)(tid >> 3) * K + ((tid & 7) ^ fsw) * 8;
    const unsigned short* gBsrc = Bm + n0 * K + (size_t)(tid >> 3) * K + ((tid & 7) ^ fsw) * 8;
    char* stA_run = (char*)As + 16384 + tid * 16;   // A(t+1) -> other buffer
    char* stB_run = (char*)Bs + tid * 16;           // B(t+2) -> same-parity buffer
    const unsigned short* gA_run = gAsrc + 64;
    const unsigned short* gB_run = gBsrc + 128;
    int dirA = 16384, dirB = 16384;

    // prologue: A(0) h0,h1 | B(0) h0,h1 | B(1) h0,h1 (6 loads); VMW(2) => tile 0 landed
    STG_64(gAsrc, 0, (char*)As + tid * 16);
    STG_64(gAsrc, 1, (char*)As + tid * 16);
    STG_64(gBsrc, 0, (char*)Bs + tid * 16);
    STG_64(gBsrc, 1, (char*)Bs + tid * 16);
    STG_64(gBsrc + 64, 0, (char*)Bs + 16384 + tid * 16);
    STG_64(gBsrc + 64, 1, (char*)Bs + 16384 + tid * 16);
    VMW(2);
    BAR();

    bf16x8 ak0[2], ak1[2], b0[4], b1[4];
    LDA2O(ak0, 0, 0);
    LDB4O(b0, 0, 0);

    for (int t = 0; t < nt; ++t) {
        // ---- phase 0 ----
        STG_64(gA_run, 0, stA_run);
        PRIO1();
        LDB4O(b1, 1, 0);
        MFMA4K(ak0, b0, 0, 0);
        PRIO0();

        // ---- phase 1 ----
        STG_64(gA_run, 1, stA_run);
        PRIO1();
        LDA2O(ak1, 1, 0);
        MFMA4K(ak0, b1, 2, 0);
        PRIO0();
        BAR();

        // ---- phase 2 ----
        STG_64(gB_run, 0, stB_run);
        PRIO1();
        MFMA4K(ak1, b0, 0, 1);
        PRIO0();
        VMW(1);
        BAR();

        // ---- phase 3 ----
        STG_64(gB_run, 1, stB_run);
        PRIO1();
        LDA2O(ak0, 0, dirA);
        LDB4O(b0, 0, dirB);
        MFMA4K(ak1, b1, 2, 1);
        PRIO0();

        gA_run += 64; gB_run += 64;
        pA0 += dirA; pA1 += dirA; pB0 += dirB; pB1 += dirB;
        stA_run -= dirA; stB_run += dirB;
        dirA = -dirA; dirB = -dirB;
    }
    VMW(0);

    // ---- epilogue ----
    #pragma unroll
    for (int mi = 0; mi < 2; mi++) {
        #pragma unroll
        for (int j = 0; j < 4; j++) {
            const int row = (int)m0 + wm * 32 + mi * 16 + lq * 4 + j;
            if (EPI == 2) {
                float sc = 1.0f / (1.0f + sqrtf(ssum[row]));
                #pragma unroll
                for (int ni = 0; ni < 4; ni++) {
                    int col = (int)n0 + wn * 64 + ni * 16 + lr;
                    if (col < C_) O0[(size_t)row * C_ + col] = acc[mi][ni][j] * sc;
                }
            } else { // EPI == 3: inf = cs*mem; xo = reach*(x+inf); ssum += xo^2
                float r = reach[row];
                float ssp = 0.0f;
                #pragma unroll
                for (int ni = 0; ni < 4; ni++) {
                    int col = (int)n0 + wn * 64 + ni * 16 + lr;
                    size_t id = (size_t)row * F_ + col;
                    float mem = acc[mi][ni][j];
                    float inf = bf2f(csrc[id]) * mem;
                    float xo = r * (bf2f(xsrcb[id]) + inf);
                    O0[id] = inf;            // out_infused (f32)
                    O2[id] = f2bf(xo);       // xo_bf for G3 (same buffer as xsrcb; RAW per-thread)
                    ssp += xo * xo;
                }
                ssp += __shfl_xor(ssp, 1);
                ssp += __shfl_xor(ssp, 2);
                ssp += __shfl_xor(ssp, 4);
                ssp += __shfl_xor(ssp, 8);
                if (lr == 0) atomicAdd(ssum + row, ssp);
            }
        }
    }
}

// ---------- softmax (bf16 in) + reach finalize ----------

__global__ __launch_bounds__(256) void k_softmax(const unsigned short* __restrict__ L,
                                                 unsigned short* __restrict__ vm,
                                                 const unsigned int* __restrict__ dmin,
                                                 float* __restrict__ reach) {
    int row = blockIdx.x, t = threadIdx.x;
    float v[4]; float mx = -1e30f;
    #pragma unroll
    for (int i = 0; i < 4; i++) {
        int col = t + i * 256;
        float val = (col < C_) ? bf2f(L[(size_t)row * CP + col]) : -1e30f;
        v[i] = val; mx = fmaxf(mx, val);
    }
    mx = blockReduce<1>(mx);
    float s = 0.f;
    #pragma unroll
    for (int i = 0; i < 4; i++) {
        int col = t + i * 256;
        v[i] = (col < C_) ? __expf(v[i] - mx) : 0.0f;
        s += v[i];
    }
    s = blockReduce<0>(s);
    float inv = 1.0f / s;
    #pragma unroll
    for (int i = 0; i < 4; i++) vm[(size_t)row * CP + t + i * 256] = f2bf(v[i] * inv);
    if (t == 0) {
        float m = __uint_as_float(dmin[row]);
        reach[row] = 10.0f / (sqrtf(m) + 1e-5f);
    }
}

// ---------- host ----------

extern "C" void kernel_launch(void* const* d_in, const int* in_sizes, int n_in,
                              void* d_out, int out_size, void* d_ws, size_t ws_size,
                              hipStream_t stream) {
    const float* x     = (const float*)d_in[0];
    const float* cent  = (const float*)d_in[1];
    const float* Whall = (const float*)d_in[2];
    const float* bhall = (const float*)d_in[3];
    const float* Wsel  = (const float*)d_in[4];
    const float* bsel  = (const float*)d_in[5];
    const float* Wcos  = (const float*)d_in[6];

    float* out_logits  = (float*)d_out;
    float* out_direct  = out_logits + (size_t)B_ * C_;
    float* out_infused = out_direct + (size_t)B_ * F_;

    char* ws = (char*)d_ws;
    unsigned short* x_bf    = (unsigned short*)(ws);                 // 33.5 MB [8192][2048]
    unsigned short* Bcat    = (unsigned short*)(ws + 33554432);      // 16 MB  [4096][2048]
    unsigned short* centT   = (unsigned short*)(ws + 50331648);      // 4 MB   [2048][1024]
    unsigned short* wcos_bf = (unsigned short*)(ws + 54525952);      // 4 MB   [1024][2048]
    unsigned short* cs_bf   = (unsigned short*)(ws + 58720256);      // 33.5 MB [8192][2048]
    float* x2    = (float*)(ws + 92274688);
    float* c2    = (float*)(ws + 92307456);
    float* reach = (float*)(ws + 92311552);
    unsigned int* dmin = (unsigned int*)(ws + 92344320);
    float* ssum  = (float*)(ws + 92377088);

    // scratch aliased onto output regions (strictly stream-ordered before final writes)
    unsigned short* hall_bf = (unsigned short*)(out_infused + (size_t)B_ * 1024); // [8192][1024] bf16
    unsigned short* vm_bf = (unsigned short*)out_logits;   // [8192][1024] bf16, dead after G2
    unsigned short* xo_bf = x_bf;                          // xo overwrites x_bf in G2 epilogue

    k_prep<<<13312, 256, 0, stream>>>(x, cent, Whall, Wsel, Wcos,
                                      x_bf, x2, out_direct, dmin, ssum,
                                      Bcat, centT, c2, wcos_bf);

    // G1: dmin | hall logits (bf16) | concept selector (M=8192, N=4096, K=2048)
    k_gemm_g1<F_><<<dim3(512), 512, 0, stream>>>(
        x_bf, Bcat, hall_bf, cs_bf, x2, c2, bhall, bsel, dmin);

    k_softmax<<<B_, 256, 0, stream>>>(hall_bf, vm_bf, dmin, reach);

    // G2: memory_feature + fused infuse/norm (M=8192, N=2048, K=1024) -> 1024 blocks, 2/CU
    k_gemmS<3, CP><<<dim3(1024), 512, 0, stream>>>(
        vm_bf, centT, out_infused, xo_bf, cs_bf, x_bf, reach, ssum);

    // G3: logits = (xo @ (16*ew)^T) * 1/(1+||xo||) (M=8192, N=1024, K=2048) -> 512 blocks, 2/CU
    k_gemmS<2, F_><<<dim3(512), 512, 0, stream>>>(
        xo_bf, wcos_bf, out_logits, nullptr, nullptr, nullptr, nullptr, ssum);

    (void)in_sizes; (void)n_in; (void)out_size; (void)ws_size;
}

// Round 10
// 299.563 us; speedup vs baseline: 1.1006x; 1.0312x over previous
//
#include <hip/hip_runtime.h>
#include <hip/hip_bf16.h>

#define B_ 8192
#define F_ 2048
#define C_ 1000
#define CP 1024

typedef __attribute__((ext_vector_type(4))) float f32x4;
typedef __attribute__((ext_vector_type(8))) short bf16x8;
typedef __attribute__((ext_vector_type(8))) unsigned short u16x8;

__device__ __forceinline__ unsigned short f2bf(float f) {
    union { float f; unsigned int u; } x; x.f = f;
    unsigned int r = x.u + 0x7fffu + ((x.u >> 16) & 1u);
    return (unsigned short)(r >> 16);
}
__device__ __forceinline__ float bf2f(unsigned short h) {
    union { unsigned int u; float f; } x; x.u = ((unsigned int)h) << 16; return x.f;
}

template<int OP>
__device__ __forceinline__ float blockReduce(float v) {
    __shared__ float s[4];
    #pragma unroll
    for (int o = 32; o; o >>= 1) {
        float u = __shfl_down(v, o);
        v = (OP == 0) ? v + u : (OP == 1) ? fmaxf(v, u) : fminf(v, u);
    }
    __syncthreads();
    if ((threadIdx.x & 63) == 0) s[threadIdx.x >> 6] = v;
    __syncthreads();
    float r = s[0];
    #pragma unroll
    for (int i = 1; i < 4; i++) r = (OP == 0) ? r + s[i] : (OP == 1) ? fmaxf(r, s[i]) : fminf(r, s[i]);
    return r;
}

__device__ __forceinline__ void async16(const void* g, void* l) {
    __builtin_amdgcn_global_load_lds(
        (const __attribute__((address_space(1))) void*)g,
        (__attribute__((address_space(3))) void*)l, 16, 0, 0);
}

// ---------- merged prep ----------

__global__ __launch_bounds__(256) void k_prep(const float* __restrict__ x,
                                              const float* __restrict__ cent,
                                              const float* __restrict__ Whall,
                                              const float* __restrict__ Wsel,
                                              const float* __restrict__ Wcos,
                                              unsigned short* __restrict__ xbf,
                                              float* __restrict__ x2,
                                              float* __restrict__ direct,
                                              unsigned int* __restrict__ dmin,
                                              float* __restrict__ ssum,
                                              unsigned short* __restrict__ Bcat,
                                              unsigned short* __restrict__ cT,
                                              float* __restrict__ c2,
                                              unsigned short* __restrict__ wcos_bf) {
    const int bid = blockIdx.x, t = threadIdx.x;

    if (bid < 8192) {
        int row = bid;
        size_t base = (size_t)row * F_ + t * 8;
        float4 a = *(const float4*)(x + base);
        float4 b = *(const float4*)(x + base + 4);
        float v[8] = {a.x, a.y, a.z, a.w, b.x, b.y, b.z, b.w};
        u16x8 u; float ss = 0.f;
        #pragma unroll
        for (int j = 0; j < 8; j++) { ss += v[j] * v[j]; u[j] = f2bf(v[j]); }
        *(u16x8*)(xbf + base) = u;
        *(float4*)(direct + base) = a;
        *(float4*)(direct + base + 4) = b;
        ss = blockReduce<0>(ss);
        if (t == 0) { x2[row] = ss; dmin[row] = 0x7f7f7f7fu; ssum[row] = 0.0f; }
    } else if (bid < 9216) {
        int row = bid - 8192;
        size_t base = (size_t)row * F_ + t * 8;
        if (row < C_) {
            float4 a = *(const float4*)(cent + base);
            float4 b = *(const float4*)(cent + base + 4);
            float v[8] = {a.x, a.y, a.z, a.w, b.x, b.y, b.z, b.w};
            u16x8 u; float ss = 0.f;
            #pragma unroll
            for (int j = 0; j < 8; j++) { ss += v[j] * v[j]; u[j] = f2bf(v[j]); }
            *(u16x8*)(Bcat + base) = u;
            #pragma unroll
            for (int j = 0; j < 8; j++) cT[(size_t)(t * 8 + j) * CP + row] = u[j];
            ss = blockReduce<0>(ss);
            if (t == 0) c2[row] = ss;
        } else {
            u16x8 u;
            #pragma unroll
            for (int j = 0; j < 8; j++) u[j] = 0;
            *(u16x8*)(Bcat + base) = u;
            #pragma unroll
            for (int j = 0; j < 8; j++) cT[(size_t)(t * 8 + j) * CP + row] = 0;
            if (t == 0) c2[row] = 0.f;
        }
    } else if (bid < 10240) {
        int row = bid - 9216;
        size_t base = (size_t)row * F_ + t * 8;
        u16x8 u;
        if (row < C_) {
            float4 a = *(const float4*)(Whall + base);
            float4 b = *(const float4*)(Whall + base + 4);
            float v[8] = {a.x, a.y, a.z, a.w, b.x, b.y, b.z, b.w};
            #pragma unroll
            for (int j = 0; j < 8; j++) u[j] = f2bf(v[j]);
        } else {
            #pragma unroll
            for (int j = 0; j < 8; j++) u[j] = 0;
        }
        *(u16x8*)(Bcat + (size_t)1024 * F_ + base) = u;
    } else if (bid < 12288) {
        int row = bid - 10240;
        size_t base = (size_t)row * F_ + t * 8;
        float4 a = *(const float4*)(Wsel + base);
        float4 b = *(const float4*)(Wsel + base + 4);
        float v[8] = {a.x, a.y, a.z, a.w, b.x, b.y, b.z, b.w};
        u16x8 u;
        #pragma unroll
        for (int j = 0; j < 8; j++) u[j] = f2bf(v[j]);
        *(u16x8*)(Bcat + (size_t)2048 * F_ + base) = u;
    } else {
        int row = bid - 12288;
        size_t base = (size_t)row * F_ + t * 8;
        u16x8 u;
        if (row < C_) {
            float4 a = *(const float4*)(Wcos + base);
            float4 b = *(const float4*)(Wcos + base + 4);
            float v[8] = {a.x, a.y, a.z, a.w, b.x, b.y, b.z, b.w};
            float ss = 0.f;
            #pragma unroll
            for (int j = 0; j < 8; j++) ss += v[j] * v[j];
            ss = blockReduce<0>(ss);
            float sc = 16.0f / sqrtf(ss);
            #pragma unroll
            for (int j = 0; j < 8; j++) u[j] = f2bf(v[j] * sc);
        } else {
            #pragma unroll
            for (int j = 0; j < 8; j++) u[j] = 0;
        }
        *(u16x8*)(wcos_bf + base) = u;
    }
}

// ---------- shared GEMM machinery (R2/R6 proven 4-phase skeleton) ----------
//   ph0: MFMA(a0,b0)  | prefetch b1  | stage A(t+1)h0
//   ph1: MFMA(a0,b1)  | prefetch a1  | stage A(t+1)h1   -> BAR (staging WAR)
//   ph2: MFMA(a1,b0)  |              | stage B(t+2)h0   -> VMW(2)+BAR (publish)
//   ph3: MFMA(a1,b1)  | prefetch a0',b0' (NEXT buffer)  | stage B(t+2)h1
// VMW(2) completes exactly A(t+1)+B(t+1), leaving B(t+2)h0 in flight.

#define BAR() __builtin_amdgcn_s_barrier()
#define VMW(N) asm volatile("s_waitcnt vmcnt(" #N ")" ::: "memory")
#define PRIO1() __builtin_amdgcn_s_setprio(1)
#define PRIO0() __builtin_amdgcn_s_setprio(0)

#define LDA8O(dst, mh, off)                                                     \
    _Pragma("unroll")                                                           \
    for (int i_ = 0; i_ < 4; i_++) {                                            \
        dst[i_ * 2 + 0] = *(const bf16x8*)(pA0 + (off) + (mh) * 8192 + i_ * 2048); \
        dst[i_ * 2 + 1] = *(const bf16x8*)(pA1 + (off) + (mh) * 8192 + i_ * 2048); \
    }

#define LDB4O(dst, nh, off)                                                     \
    _Pragma("unroll")                                                           \
    for (int i_ = 0; i_ < 2; i_++) {                                            \
        dst[i_ * 2 + 0] = *(const bf16x8*)(pB0 + (off) + (nh) * 4096 + i_ * 2048); \
        dst[i_ * 2 + 1] = *(const bf16x8*)(pB1 + (off) + (nh) * 4096 + i_ * 2048); \
    }

#define STG_HALF(gp, half, ldsbase)                                             \
    _Pragma("unroll")                                                           \
    for (int i_ = 0; i_ < 2; i_++)                                              \
        async16((gp) + ((half) * 128 + i_ * 64) * (size_t)K,                    \
                (ldsbase) + (half) * 16384 + i_ * 8192);

#define MFMA16(a, b, mi0, ni0)                                                  \
    _Pragma("unroll")                                                           \
    for (int ks_ = 0; ks_ < 2; ks_++)                                           \
        _Pragma("unroll")                                                       \
        for (int i_ = 0; i_ < 4; i_++)                                          \
            _Pragma("unroll")                                                   \
            for (int j_ = 0; j_ < 2; j_++)                                      \
                acc[(mi0) + i_][(ni0) + j_] = __builtin_amdgcn_mfma_f32_16x16x32_bf16( \
                    a[i_ * 2 + ks_], b[j_ * 2 + ks_], acc[(mi0) + i_][(ni0) + j_], 0, 0, 0);

__device__ __forceinline__ float fast_tanh(float v) {
    float t = __expf(v + v);
    return (t - 1.0f) / (t + 1.0f);
}

// ---------- G1: 256x256 GEMM, fused epilogue (dmin | hall->bf16 | tanh->bf16) ----------

template<int K>
__global__ __launch_bounds__(512, 2) void k_gemm_g1(const unsigned short* __restrict__ A,
                                                    const unsigned short* __restrict__ Bm,
                                                    unsigned short* __restrict__ hallO,
                                                    unsigned short* __restrict__ csO,
                                                    const float* __restrict__ x2,
                                                    const float* __restrict__ c2,
                                                    const float* __restrict__ bias1,
                                                    const float* __restrict__ bias2,
                                                    unsigned int* __restrict__ dmin) {
    __shared__ unsigned short As[2][256 * 64];
    __shared__ unsigned short Bs[2][256 * 64];
    constexpr int nt = K / 64;

    const int tid = threadIdx.x, lane = tid & 63, w = tid >> 6;
    const int wm = w >> 2, wn = w & 3;
    const int lr = lane & 15, lq = lane >> 4;
    const int e2 = (lr >> 2) & 1, e3 = lr & 3;

    const int nbn2 = (gridDim.x >> 5) >> 1;
    const int xcd = blockIdx.x & 7, idx = blockIdx.x >> 3;
    const int bm = (xcd & 3) * 8 + (idx & 7);
    const int bn = (xcd >> 2) * nbn2 + (idx >> 3);
    const size_t m0 = (size_t)bm * 256, n0 = (size_t)bn * 256;

    f32x4 acc[8][4] = {};

    const char* pA0 = (const char*)As + wm * 16384 + lr * 128 + (lq ^ e3) * 16 + (0 ^ e2) * 64;
    const char* pA1 = (const char*)As + wm * 16384 + lr * 128 + (lq ^ e3) * 16 + (1 ^ e2) * 64;
    const char* pB0 = (const char*)Bs + wn * 8192 + lr * 128 + (lq ^ e3) * 16 + (0 ^ e2) * 64;
    const char* pB1 = (const char*)Bs + wn * 8192 + lr * 128 + (lq ^ e3) * 16 + (1 ^ e2) * 64;

    const int fsw = (tid >> 3) & 7;
    const unsigned short* gAsrc = A + m0 * K + (size_t)(tid >> 3) * K + ((tid & 7) ^ fsw) * 8;
    const unsigned short* gBsrc = Bm + n0 * K + (size_t)(tid >> 3) * K + ((tid & 7) ^ fsw) * 8;
    char* stA_run = (char*)As + 32768 + tid * 16;
    char* stB_run = (char*)Bs + tid * 16;
    const unsigned short* gA_run = gAsrc + 64;
    const unsigned short* gB_run = gBsrc + 128;
    int dir = 32768;

    STG_HALF(gAsrc, 0, (char*)As + tid * 16);
    STG_HALF(gAsrc, 1, (char*)As + tid * 16);
    STG_HALF(gBsrc, 0, (char*)Bs + tid * 16);
    STG_HALF(gBsrc, 1, (char*)Bs + tid * 16);
    STG_HALF(gBsrc + 64, 0, (char*)Bs + 32768 + tid * 16);
    STG_HALF(gBsrc + 64, 1, (char*)Bs + 32768 + tid * 16);
    VMW(4);
    BAR();

    bf16x8 a0[8], a1[8], b0[4], b1[4];
    LDA8O(a0, 0, 0);
    LDB4O(b0, 0, 0);

    for (int t = 0; t < nt; ++t) {
        // ---- phase 0 ----
        STG_HALF(gA_run, 0, stA_run);
        PRIO1();
        LDB4O(b1, 1, 0);
        MFMA16(a0, b0, 0, 0);
        PRIO0();

        // ---- phase 1 ----
        STG_HALF(gA_run, 1, stA_run);
        PRIO1();
        LDA8O(a1, 1, 0);
        MFMA16(a0, b1, 0, 2);
        PRIO0();
        BAR();   // staging-WAR barrier

        // ---- phase 2 ----
        STG_HALF(gB_run, 0, stB_run);
        PRIO1();
        MFMA16(a1, b0, 4, 0);
        PRIO0();
        VMW(2);
        BAR();   // publish barrier: A(t+1)+B(t+1) visible

        // ---- phase 3 ----
        STG_HALF(gB_run, 1, stB_run);
        PRIO1();
        LDA8O(a0, 0, dir);
        LDB4O(b0, 0, dir);
        MFMA16(a1, b1, 4, 2);
        PRIO0();

        gA_run += 64; gB_run += 64;
        pA0 += dir; pA1 += dir; pB0 += dir; pB1 += dir;
        stB_run += dir; stA_run -= dir;
        dir = -dir;
    }
    VMW(0);

    // ---- epilogue ----
    const int segc = (n0 >= 2048) ? 2 : (int)(n0 >> 10);

    #pragma unroll
    for (int mi = 0; mi < 8; mi++) {
        #pragma unroll
        for (int j = 0; j < 4; j++) {
            const int row = (int)m0 + wm * 128 + mi * 16 + lq * 4 + j;
            if (segc == 0) {
                float x2r = x2[row];
                float mn = 1e30f;
                #pragma unroll
                for (int ni = 0; ni < 4; ni++) {
                    int col = (int)n0 + wn * 64 + ni * 16 + lr;
                    float d = fmaxf(x2r - 2.0f * acc[mi][ni][j] + c2[col], 0.0f);
                    if (col >= C_) d = 1e30f;
                    mn = fminf(mn, d);
                }
                mn = fminf(mn, __shfl_xor(mn, 1));
                mn = fminf(mn, __shfl_xor(mn, 2));
                mn = fminf(mn, __shfl_xor(mn, 4));
                mn = fminf(mn, __shfl_xor(mn, 8));
                if (lr == 0) atomicMin(dmin + row, __float_as_uint(mn));
            } else if (segc == 1) {
                #pragma unroll
                for (int ni = 0; ni < 4; ni++) {
                    int col = (int)n0 + wn * 64 + ni * 16 + lr;
                    int c = col - 1024;
                    hallO[(size_t)row * 1024 + c] = f2bf(acc[mi][ni][j] + (c < C_ ? bias1[c] : 0.0f));
                }
            } else {
                #pragma unroll
                for (int ni = 0; ni < 4; ni++) {
                    int col = (int)n0 + wn * 64 + ni * 16 + lr;
                    int c = col - 2048;
                    csO[(size_t)row * F_ + c] = f2bf(fast_tanh(acc[mi][ni][j] + bias2[c]));
                }
            }
        }
    }
}

// ---------- 128x256 variant (R6 proven), EPI 2 = G3 logits, 3 = G2 fused ----------

#define STG_A128(gp, half, ldsbase)                                             \
    async16((gp) + ((half) * 64) * (size_t)K, (ldsbase) + (half) * 8192);

#define LDA4O(dst, kk, off)                                                     \
    _Pragma("unroll")                                                           \
    for (int i_ = 0; i_ < 4; i_++)                                              \
        dst[i_] = *(const bf16x8*)(((kk) ? pA1 : pA0) + (off) + i_ * 2048);

#define MFMA8K(av, bv, ni0, ks)                                                 \
    _Pragma("unroll")                                                           \
    for (int i_ = 0; i_ < 4; i_++)                                              \
        _Pragma("unroll")                                                       \
        for (int j_ = 0; j_ < 2; j_++)                                          \
            acc[i_][(ni0) + j_] = __builtin_amdgcn_mfma_f32_16x16x32_bf16(      \
                av[i_], bv[j_ * 2 + (ks)], acc[i_][(ni0) + j_], 0, 0, 0);

template<int EPI, int K>
__global__ __launch_bounds__(512, 2) void k_gemm128(const unsigned short* __restrict__ A,
                                                    const unsigned short* __restrict__ Bm,
                                                    float* __restrict__ O0,
                                                    unsigned short* __restrict__ O2,
                                                    const unsigned short* __restrict__ csrc,
                                                    const unsigned short* __restrict__ xsrcb,
                                                    const float* __restrict__ reach,
                                                    float* __restrict__ ssum) {
    __shared__ unsigned short As[2][128 * 64];   // 2 x 16 KiB
    __shared__ unsigned short Bs[2][256 * 64];   // 2 x 32 KiB
    constexpr int nt = K / 64;
    constexpr int nbn = (EPI == 3) ? 8 : 4;      // N-tiles (G2: N=2048, G3: N=1024)

    const int tid = threadIdx.x, lane = tid & 63, w = tid >> 6;
    const int wm = w >> 2, wn = w & 3;
    const int lr = lane & 15, lq = lane >> 4;
    const int e2 = (lr >> 2) & 1, e3 = lr & 3;

    // grid = 64*nbn blocks; per-XCD: 8 contiguous bm x all bn (bijective)
    const int xcd = blockIdx.x & 7, idx = blockIdx.x >> 3;
    const int bm = xcd * 8 + idx / nbn;
    const int bn = idx % nbn;
    const size_t m0 = (size_t)bm * 128, n0 = (size_t)bn * 256;

    f32x4 acc[4][4] = {};

    const char* pA0 = (const char*)As + wm * 8192 + lr * 128 + (lq ^ e3) * 16 + (0 ^ e2) * 64;
    const char* pA1 = (const char*)As + wm * 8192 + lr * 128 + (lq ^ e3) * 16 + (1 ^ e2) * 64;
    const char* pB0 = (const char*)Bs + wn * 8192 + lr * 128 + (lq ^ e3) * 16 + (0 ^ e2) * 64;
    const char* pB1 = (const char*)Bs + wn * 8192 + lr * 128 + (lq ^ e3) * 16 + (1 ^ e2) * 64;

    const int fsw = (tid >> 3) & 7;
    const unsigned short* gAsrc = A + m0 * K + (size_t)(tid >> 3) * K + ((tid & 7) ^ fsw) * 8;
    const unsigned short* gBsrc = Bm + n0 * K + (size_t)(tid >> 3) * K + ((tid & 7) ^ fsw) * 8;
    char* stA_run = (char*)As + 16384 + tid * 16;   // A(t+1) -> other buffer
    char* stB_run = (char*)Bs + tid * 16;           // B(t+2) -> same-parity buffer
    const unsigned short* gA_run = gAsrc + 64;
    const unsigned short* gB_run = gBsrc + 128;
    int dirA = 16384, dirB = 32768;

    // prologue: A(0) (2 loads), B(0) (4), B(1) (4); VMW(4) => A(0)+B(0) landed
    STG_A128(gAsrc, 0, (char*)As + tid * 16);
    STG_A128(gAsrc, 1, (char*)As + tid * 16);
    STG_HALF(gBsrc, 0, (char*)Bs + tid * 16);
    STG_HALF(gBsrc, 1, (char*)Bs + tid * 16);
    STG_HALF(gBsrc + 64, 0, (char*)Bs + 32768 + tid * 16);
    STG_HALF(gBsrc + 64, 1, (char*)Bs + 32768 + tid * 16);
    VMW(4);
    BAR();

    bf16x8 ak0[4], ak1[4], b0[4], b1[4];
    LDA4O(ak0, 0, 0);
    LDB4O(b0, 0, 0);

    for (int t = 0; t < nt; ++t) {
        // ---- phase 0 ----
        STG_A128(gA_run, 0, stA_run);
        PRIO1();
        LDB4O(b1, 1, 0);
        MFMA8K(ak0, b0, 0, 0);
        PRIO0();

        // ---- phase 1 ----
        STG_A128(gA_run, 1, stA_run);
        PRIO1();
        LDA4O(ak1, 1, 0);
        MFMA8K(ak0, b1, 2, 0);
        PRIO0();
        BAR();

        // ---- phase 2 ----
        STG_HALF(gB_run, 0, stB_run);
        PRIO1();
        MFMA8K(ak1, b0, 0, 1);
        PRIO0();
        VMW(2);
        BAR();

        // ---- phase 3 ----
        STG_HALF(gB_run, 1, stB_run);
        PRIO1();
        LDA4O(ak0, 0, dirA);
        LDB4O(b0, 0, dirB);
        MFMA8K(ak1, b1, 2, 1);
        PRIO0();

        gA_run += 64; gB_run += 64;
        pA0 += dirA; pA1 += dirA; pB0 += dirB; pB1 += dirB;
        stA_run -= dirA; stB_run += dirB;
        dirA = -dirA; dirB = -dirB;
    }
    VMW(0);

    // ---- epilogue ----
    #pragma unroll
    for (int mi = 0; mi < 4; mi++) {
        #pragma unroll
        for (int j = 0; j < 4; j++) {
            const int row = (int)m0 + wm * 64 + mi * 16 + lq * 4 + j;
            if (EPI == 2) {
                float sc = 1.0f / (1.0f + sqrtf(ssum[row]));
                #pragma unroll
                for (int ni = 0; ni < 4; ni++) {
                    int col = (int)n0 + wn * 64 + ni * 16 + lr;
                    if (col < C_) O0[(size_t)row * C_ + col] = acc[mi][ni][j] * sc;
                }
            } else { // EPI == 3: inf = cs*mem; xo = reach*(x+inf); ssum += xo^2
                float r = reach[row];
                float ssp = 0.0f;
                #pragma unroll
                for (int ni = 0; ni < 4; ni++) {
                    int col = (int)n0 + wn * 64 + ni * 16 + lr;
                    size_t id = (size_t)row * F_ + col;
                    float mem = acc[mi][ni][j];
                    float inf = bf2f(csrc[id]) * mem;
                    float xo = r * (bf2f(xsrcb[id]) + inf);
                    O0[id] = inf;            // out_infused (f32)
                    O2[id] = f2bf(xo);       // xo_bf for G3 (same buffer as xsrcb; RAW per-thread)
                    ssp += xo * xo;
                }
                ssp += __shfl_xor(ssp, 1);
                ssp += __shfl_xor(ssp, 2);
                ssp += __shfl_xor(ssp, 4);
                ssp += __shfl_xor(ssp, 8);
                if (lr == 0) atomicAdd(ssum + row, ssp);
            }
        }
    }
}

// ---------- softmax (bf16 in) + reach finalize ----------

__global__ __launch_bounds__(256) void k_softmax(const unsigned short* __restrict__ L,
                                                 unsigned short* __restrict__ vm,
                                                 const unsigned int* __restrict__ dmin,
                                                 float* __restrict__ reach) {
    int row = blockIdx.x, t = threadIdx.x;
    float v[4]; float mx = -1e30f;
    #pragma unroll
    for (int i = 0; i < 4; i++) {
        int col = t + i * 256;
        float val = (col < C_) ? bf2f(L[(size_t)row * CP + col]) : -1e30f;
        v[i] = val; mx = fmaxf(mx, val);
    }
    mx = blockReduce<1>(mx);
    float s = 0.f;
    #pragma unroll
    for (int i = 0; i < 4; i++) {
        int col = t + i * 256;
        v[i] = (col < C_) ? __expf(v[i] - mx) : 0.0f;
        s += v[i];
    }
    s = blockReduce<0>(s);
    float inv = 1.0f / s;
    #pragma unroll
    for (int i = 0; i < 4; i++) vm[(size_t)row * CP + t + i * 256] = f2bf(v[i] * inv);
    if (t == 0) {
        float m = __uint_as_float(dmin[row]);
        reach[row] = 10.0f / (sqrtf(m) + 1e-5f);
    }
}

// ---------- host ----------

extern "C" void kernel_launch(void* const* d_in, const int* in_sizes, int n_in,
                              void* d_out, int out_size, void* d_ws, size_t ws_size,
                              hipStream_t stream) {
    const float* x     = (const float*)d_in[0];
    const float* cent  = (const float*)d_in[1];
    const float* Whall = (const float*)d_in[2];
    const float* bhall = (const float*)d_in[3];
    const float* Wsel  = (const float*)d_in[4];
    const float* bsel  = (const float*)d_in[5];
    const float* Wcos  = (const float*)d_in[6];

    float* out_logits  = (float*)d_out;
    float* out_direct  = out_logits + (size_t)B_ * C_;
    float* out_infused = out_direct + (size_t)B_ * F_;

    char* ws = (char*)d_ws;
    unsigned short* x_bf    = (unsigned short*)(ws);                 // 33.5 MB [8192][2048]
    unsigned short* Bcat    = (unsigned short*)(ws + 33554432);      // 16 MB  [4096][2048]
    unsigned short* centT   = (unsigned short*)(ws + 50331648);      // 4 MB   [2048][1024]
    unsigned short* wcos_bf = (unsigned short*)(ws + 54525952);      // 4 MB   [1024][2048]
    unsigned short* cs_bf   = (unsigned short*)(ws + 58720256);      // 33.5 MB [8192][2048]
    float* x2    = (float*)(ws + 92274688);
    float* c2    = (float*)(ws + 92307456);
    float* reach = (float*)(ws + 92311552);
    unsigned int* dmin = (unsigned int*)(ws + 92344320);
    float* ssum  = (float*)(ws + 92377088);

    // scratch aliased onto output regions (strictly stream-ordered before final writes)
    unsigned short* hall_bf = (unsigned short*)(out_infused + (size_t)B_ * 1024); // [8192][1024] bf16
    unsigned short* vm_bf = (unsigned short*)out_logits;   // [8192][1024] bf16, dead after G2
    unsigned short* xo_bf = x_bf;                          // xo overwrites x_bf in G2 epilogue

    k_prep<<<13312, 256, 0, stream>>>(x, cent, Whall, Wsel, Wcos,
                                      x_bf, x2, out_direct, dmin, ssum,
                                      Bcat, centT, c2, wcos_bf);

    // G1: dmin | hall logits (bf16) | concept selector (M=8192, N=4096, K=2048)
    k_gemm_g1<F_><<<dim3(512), 512, 0, stream>>>(
        x_bf, Bcat, hall_bf, cs_bf, x2, c2, bhall, bsel, dmin);

    k_softmax<<<B_, 256, 0, stream>>>(hall_bf, vm_bf, dmin, reach);

    // G2: memory_feature + fused infuse/norm (M=8192, N=2048, K=1024) -> 512 blocks
    k_gemm128<3, CP><<<dim3(512), 512, 0, stream>>>(
        vm_bf, centT, out_infused, xo_bf, cs_bf, x_bf, reach, ssum);

    // G3: logits = (xo @ (16*ew)^T) * 1/(1+||xo||) (M=8192, N=1024, K=2048) -> 256 blocks
    k_gemm128<2, F_><<<dim3(256), 512, 0, stream>>>(
        xo_bf, wcos_bf, out_logits, nullptr, nullptr, nullptr, nullptr, ssum);

    (void)in_sizes; (void)n_in; (void)out_size; (void)ws_size;
}